// Round 4
// baseline (20.613 us; speedup 1.0000x reference)
//
#include <hip/hip_runtime.h>

#define NUM_NODES 10000
#define TSTEPS 1440
#define VCOLS 360          // 1440/4 real float4 columns
#define PVC 384            // padded float4 stride of one partial row
#define NPART 512          // partial rows (500 real + 12 zero pad blocks)
#define ROWS_PER_BLOCK 20  // 500 * 20 = 10000 rows exactly
#define REAL_BLOCKS 500

__device__ __forceinline__ void f4add(float4& a, const float4 b) {
    a.x += b.x; a.y += b.y; a.z += b.z; a.w += b.w;
}

// Stage 1: partial column-sums of noise [10000, 1440] -> part [512][384] f4.
// Manual 4-deep unroll with 4 INDEPENDENT accumulators: rounds 1-2 showed
// VGPR_Count=16, i.e. the compiler serialized the loads behind one acc chain;
// 4 temps + 4 accs keeps ~4 float4 loads in flight per thread (~40 VGPR,
// still 6 waves/block full occupancy). All 384x512 threads write (zeros for
// pad cols/blocks) so stage 2 never reads 0xAA poison.
__global__ __launch_bounds__(384) void partial_sum_kernel(
        const float* __restrict__ noise, float4* __restrict__ part) {
    int vc = threadIdx.x;            // 0..383
    int b  = blockIdx.x;             // 0..511
    float4 a0 = make_float4(0.f,0.f,0.f,0.f), a1 = a0, a2 = a0, a3 = a0;
    if (b < REAL_BLOCKS && vc < VCOLS) {
        const float4* p = (const float4*)noise
                        + (size_t)b * ROWS_PER_BLOCK * VCOLS + vc;
        #pragma unroll
        for (int k = 0; k < ROWS_PER_BLOCK / 4; ++k) {
            float4 v0 = p[0 * VCOLS];
            float4 v1 = p[1 * VCOLS];
            float4 v2 = p[2 * VCOLS];
            float4 v3 = p[3 * VCOLS];
            p += 4 * VCOLS;
            f4add(a0, v0); f4add(a1, v1); f4add(a2, v2); f4add(a3, v3);
        }
    }
    f4add(a0, a1); f4add(a2, a3); f4add(a0, a2);
    part[(size_t)b * PVC + vc] = a0;
}

// Stage 2: reduce 512 partials per column + fused finalize, FULLY COALESCED
// (round-3 wave-per-column had lane stride 5760B -> 64 lines/instr -> ~46 MB
// of line traffic). Block = 8 j-lanes x 32 float4-cols; a wave load is two
// contiguous 512B segments; exact 3 MB total read. Cross-j combine in LDS.
// overall[t] = 0.8*colmean + 0.5 + 0.3*sin(2pi*(10/3600)*time[t])
//   (mean over nodes of sin(theta_t + i*2pi/N) is exactly 0; roots of unity)
// encrypted[t] = sin(0.5*overall[t]); out = [encrypted(1440) | overall(1440)]
__global__ __launch_bounds__(256) void reduce_finalize_kernel(
        const float* __restrict__ time_tensor,
        const float4* __restrict__ part,
        float* __restrict__ out) {
    int tid = threadIdx.x;
    int c4  = tid & 31;              // float4-col within block tile
    int jr  = tid >> 5;              // 0..7 j-lane
    int c4g = blockIdx.x * 32 + c4;  // global float4-col 0..383

    float4 acc0 = make_float4(0.f,0.f,0.f,0.f), acc1 = acc0;
    const float4* p = part + (size_t)jr * PVC + c4g;
    #pragma unroll 4
    for (int k = 0; k < NPART / 16; ++k) {    // j = jr + 8*(2k), jr + 8*(2k+1)
        float4 v0 = p[0];
        float4 v1 = p[8 * PVC];
        p += 16 * PVC;
        f4add(acc0, v0); f4add(acc1, v1);
    }
    f4add(acc0, acc1);

    __shared__ float4 red[8][32];
    red[jr][c4] = acc0;
    __syncthreads();

    if (jr == 0 && c4g < VCOLS) {
        float4 s = red[0][c4];
        #pragma unroll
        for (int r = 1; r < 8; ++r) f4add(s, red[r][c4]);
        const float TWO_PI = 6.2831853071795864769f;
        const float BWF = 10.0f / 3600.0f;
        const float INV_N = 1.0f / NUM_NODES;
        float4 tm = ((const float4*)time_tensor)[c4g];
        float4 ov, en;
        ov.x = 0.8f * (s.x * INV_N) + 0.5f + 0.3f * sinf(TWO_PI * BWF * tm.x);
        ov.y = 0.8f * (s.y * INV_N) + 0.5f + 0.3f * sinf(TWO_PI * BWF * tm.y);
        ov.z = 0.8f * (s.z * INV_N) + 0.5f + 0.3f * sinf(TWO_PI * BWF * tm.z);
        ov.w = 0.8f * (s.w * INV_N) + 0.5f + 0.3f * sinf(TWO_PI * BWF * tm.w);
        en.x = sinf(0.5f * ov.x);
        en.y = sinf(0.5f * ov.y);
        en.z = sinf(0.5f * ov.z);
        en.w = sinf(0.5f * ov.w);
        ((float4*)out)[TSTEPS / 4 + c4g] = ov;   // overall  at [1440, 2880)
        ((float4*)out)[c4g] = en;                // encrypted at [0, 1440)
    }
}

extern "C" void kernel_launch(void* const* d_in, const int* in_sizes, int n_in,
                              void* d_out, int out_size, void* d_ws, size_t ws_size,
                              hipStream_t stream) {
    const float* time_tensor = (const float*)d_in[0];   // [1440]
    const float* noise       = (const float*)d_in[1];   // [10000, 1440]
    float* out   = (float*)d_out;                       // [2880]
    float4* part = (float4*)d_ws;                       // 512*384 float4 = 3 MB (ws = 256 MiB)

    partial_sum_kernel<<<NPART, 384, 0, stream>>>(noise, part);
    reduce_finalize_kernel<<<PVC / 32, 256, 0, stream>>>(time_tensor, part, out);
}

// Round 5
// 19.887 us; speedup vs baseline: 1.0365x; 1.0365x over previous
//
#include <hip/hip_runtime.h>

#define NUM_NODES 10000
#define TSTEPS 1440
#define VCOLS 360          // 1440/4 real float4 columns
#define PVC 384            // padded float4 stride of one partial row
#define NPART 1024         // partial rows (1000 real + 24 zero pads)
#define REAL_BLOCKS 1000
#define ROWS_PER_BLOCK 10  // 1000 * 10 = 10000 rows exactly

__device__ __forceinline__ void f4add(float4& a, const float4 b) {
    a.x += b.x; a.y += b.y; a.z += b.z; a.w += b.w;
}

// Stage 1: partial column-sums of noise [10000,1440] -> part[1024][384] f4.
// Round-4 lesson: the limiter was GRID SIZE (512 blocks = 2/CU = 12 waves/CU),
// not per-thread ILP. 1024 blocks = 4/CU = 24 waves/CU. Each thread issues 10
// independent float4 loads (static v[] -> registers, ~56 VGPR) then sums.
// Every (b, vc) entry is written (zeros for pads) so stage 2 never sees 0xAA.
__global__ __launch_bounds__(384) void partial_sum_kernel(
        const float* __restrict__ noise, float4* __restrict__ part) {
    int vc = threadIdx.x;            // 0..383
    int b  = blockIdx.x;             // 0..1023
    float4 acc = make_float4(0.f, 0.f, 0.f, 0.f);
    if (b < REAL_BLOCKS && vc < VCOLS) {
        const float4* p = (const float4*)noise
                        + (size_t)b * ROWS_PER_BLOCK * VCOLS + vc;
        float4 v[ROWS_PER_BLOCK];
        #pragma unroll
        for (int i = 0; i < ROWS_PER_BLOCK; ++i) v[i] = p[i * VCOLS];
        #pragma unroll
        for (int i = 0; i < ROWS_PER_BLOCK; ++i) f4add(acc, v[i]);
    }
    part[(size_t)b * PVC + vc] = acc;
}

// Stage 2: reduce 1024 partials/column + fused finalize.
// Round-4 lesson: 12 blocks x 64 loads/thread was latency-bound (~4-5 us).
// Now 90 blocks x 512 threads; thread = (c4 = tid&3, jr = tid>>2 in 0..127);
// each thread sums only 8 rows (64B-aligned segments), LDS tree 128->16,
// wave-0 shuffle 16->1, lanes 0-3 finalize one float4 column each.
// overall[t] = 0.8*colmean + 0.5 + 0.3*sin(2pi*(10/3600)*time[t])
//   (mean over nodes of sin(theta_t + i*2pi/N) is exactly 0: equally spaced
//    phases over a full circle -> sum of N-th roots of unity = 0)
// encrypted[t] = sin(0.5*overall[t]); out = [encrypted(1440) | overall(1440)]
__global__ __launch_bounds__(512) void reduce_finalize_kernel(
        const float* __restrict__ time_tensor,
        const float4* __restrict__ part,
        float* __restrict__ out) {
    int tid = threadIdx.x;
    int c4  = tid & 3;               // float4-col within block tile (0..3)
    int jr  = tid >> 2;              // 0..127
    int c4g = blockIdx.x * 4 + c4;   // global float4-col 0..359

    float4 a0 = make_float4(0.f, 0.f, 0.f, 0.f), a1 = a0;
    const float4* p = part + (size_t)jr * PVC + c4g;
    #pragma unroll
    for (int k = 0; k < NPART / 256; ++k) {   // 4 iters x 2 independent loads
        float4 v0 = p[0];
        float4 v1 = p[(size_t)128 * PVC];
        p += (size_t)256 * PVC;
        f4add(a0, v0); f4add(a1, v1);
    }
    f4add(a0, a1);

    __shared__ float4 red[128][4];
    red[jr][c4] = a0;
    __syncthreads();

    if (tid < 64) {                  // wave 0: sub = tid>>2 (0..15), c4 = tid&3
        float4 s = make_float4(0.f, 0.f, 0.f, 0.f);
        #pragma unroll
        for (int k = 0; k < 8; ++k) f4add(s, red[(tid >> 2) + 16 * k][tid & 3]);
        #pragma unroll
        for (int off = 32; off >= 4; off >>= 1) {
            s.x += __shfl_down(s.x, off, 64);
            s.y += __shfl_down(s.y, off, 64);
            s.z += __shfl_down(s.z, off, 64);
            s.w += __shfl_down(s.w, off, 64);
        }
        if (tid < 4) {               // lane l holds column c4 = l
            int cg = blockIdx.x * 4 + tid;
            const float TWO_PI = 6.2831853071795864769f;
            const float BWF = 10.0f / 3600.0f;
            const float INV_N = 1.0f / NUM_NODES;
            float4 tm = ((const float4*)time_tensor)[cg];
            float4 ov, en;
            ov.x = 0.8f * (s.x * INV_N) + 0.5f + 0.3f * sinf(TWO_PI * BWF * tm.x);
            ov.y = 0.8f * (s.y * INV_N) + 0.5f + 0.3f * sinf(TWO_PI * BWF * tm.y);
            ov.z = 0.8f * (s.z * INV_N) + 0.5f + 0.3f * sinf(TWO_PI * BWF * tm.z);
            ov.w = 0.8f * (s.w * INV_N) + 0.5f + 0.3f * sinf(TWO_PI * BWF * tm.w);
            en.x = sinf(0.5f * ov.x);
            en.y = sinf(0.5f * ov.y);
            en.z = sinf(0.5f * ov.z);
            en.w = sinf(0.5f * ov.w);
            ((float4*)out)[TSTEPS / 4 + cg] = ov;   // overall   [1440, 2880)
            ((float4*)out)[cg] = en;                // encrypted [0, 1440)
        }
    }
}

extern "C" void kernel_launch(void* const* d_in, const int* in_sizes, int n_in,
                              void* d_out, int out_size, void* d_ws, size_t ws_size,
                              hipStream_t stream) {
    const float* time_tensor = (const float*)d_in[0];   // [1440]
    const float* noise       = (const float*)d_in[1];   // [10000, 1440]
    float* out   = (float*)d_out;                       // [2880]
    float4* part = (float4*)d_ws;                       // 1024*384 f4 = 6 MB (ws = 256 MiB)

    partial_sum_kernel<<<NPART, 384, 0, stream>>>(noise, part);
    reduce_finalize_kernel<<<VCOLS / 4, 512, 0, stream>>>(time_tensor, part, out);
}